// Round 1
// baseline (823.899 us; speedup 1.0000x reference)
//
#include <hip/hip_runtime.h>
#include <hip/hip_bf16.h>

typedef __attribute__((ext_vector_type(8))) short short8v;
typedef __attribute__((ext_vector_type(4))) float f32x4;
typedef __attribute__((ext_vector_type(4))) unsigned short us4;
typedef __attribute__((ext_vector_type(8))) unsigned short us8;

#define LDA 264  // 256 + 8 bf16 pad: keeps 16B alignment, breaks bank aliasing

__device__ __forceinline__ unsigned short f2bf(float f) {
  union { float f; unsigned int u; } x; x.f = f;
  return (unsigned short)((x.u + 0x7fffu + ((x.u >> 16) & 1u)) >> 16);
}

// q = (hs@Wq+bq)/sqrt(256) as bf16 [b][n][d];  vT = (hs@Wv+bv)^T as bf16 [b][d][n]
__global__ __launch_bounds__(256) void prep_qv(
    const float* __restrict__ hs, const float* __restrict__ Wq,
    const float* __restrict__ bq, const float* __restrict__ Wv,
    const float* __restrict__ bv, unsigned short* __restrict__ qo,
    unsigned short* __restrict__ vT) {
  __shared__ float rows[8][256];
  const int tid = threadIdx.x;
  const int g0 = blockIdx.x * 8;
#pragma unroll
  for (int j = 0; j < 8; j++) rows[j][tid] = hs[(size_t)(g0 + j) * 256 + tid];
  __syncthreads();
  float aq[8], av[8];
#pragma unroll
  for (int j = 0; j < 8; j++) { aq[j] = 0.f; av[j] = 0.f; }
  for (int i = 0; i < 256; i++) {
    float wq = Wq[i * 256 + tid];
    float wv = Wv[i * 256 + tid];
#pragma unroll
    for (int j = 0; j < 8; j++) {
      aq[j] = fmaf(rows[j][i], wq, aq[j]);
      av[j] = fmaf(rows[j][i], wv, av[j]);
    }
  }
  const int bb = g0 >> 8, n0 = g0 & 255;
  const float bqs = bq[tid], bvs = bv[tid];
#pragma unroll
  for (int j = 0; j < 8; j++)
    qo[(bb * 256 + n0 + j) * 256 + tid] = f2bf((aq[j] + bqs) * 0.0625f);
  us8 vp;
#pragma unroll
  for (int j = 0; j < 8; j++) vp[j] = f2bf(av[j] + bvs);
  *(us8*)(vT + (bb * 256 + tid) * 256 + n0) = vp;
}

__global__ __launch_bounds__(256) void conv_w(
    const float* __restrict__ Wk, const float* __restrict__ Wo,
    unsigned short* __restrict__ WkT, unsigned short* __restrict__ WoT) {
  const int dout = blockIdx.x, din = threadIdx.x;
  WkT[dout * 256 + din] = f2bf(Wk[din * 256 + dout]);
  WoT[dout * 256 + din] = f2bf(Wo[din * 256 + dout]);
}

// 64x256 = (64x256 A from LDS) @ (256x256 B^T from global, row-major [col][k])
__device__ __forceinline__ void mm64x256(
    const unsigned short* sAp, const unsigned short* __restrict__ Bg,
    int w, int l16, int lhi, f32x4 acc[4][4]) {
#pragma unroll
  for (int rt = 0; rt < 4; rt++)
#pragma unroll
    for (int nt = 0; nt < 4; nt++) acc[rt][nt] = (f32x4){0.f, 0.f, 0.f, 0.f};
#pragma unroll 2
  for (int k0 = 0; k0 < 256; k0 += 32) {
    const int kk = k0 + lhi * 8;
    short8v a[4], bfr[4];
#pragma unroll
    for (int rt = 0; rt < 4; rt++)
      a[rt] = *(const short8v*)(sAp + (rt * 16 + l16) * LDA + kk);
#pragma unroll
    for (int nt = 0; nt < 4; nt++)
      bfr[nt] = *(const short8v*)(Bg + (w * 64 + nt * 16 + l16) * 256 + kk);
#pragma unroll
    for (int rt = 0; rt < 4; rt++)
#pragma unroll
      for (int nt = 0; nt < 4; nt++)
        acc[rt][nt] = __builtin_amdgcn_mfma_f32_16x16x32_bf16(
            a[rt], bfr[nt], acc[rt][nt], 0, 0, 0);
  }
}

// One block: 64 r-rows of one (b,l) pair, full fused pipeline.
__global__ __launch_bounds__(256, 2) void pair_attn(
    const float* __restrict__ S, const float* __restrict__ bk,
    const float* __restrict__ bo, const float* __restrict__ gamma,
    const float* __restrict__ beta, const unsigned short* __restrict__ q,
    const unsigned short* __restrict__ vT,
    const unsigned short* __restrict__ WkT,
    const unsigned short* __restrict__ WoT, float* __restrict__ out) {
  __shared__ unsigned short sA[64 * LDA];
  __shared__ unsigned short sB[64 * LDA];
  __shared__ float sRed[64 * 8];

  const int tid = threadIdx.x;
  const int w = tid >> 6;
  const int lane = tid & 63;
  const int l16 = lane & 15;
  const int lhi = lane >> 4;
  const int idx = blockIdx.x;
  const int rblk = idx & 3;
  const int lrow = (idx >> 2) & 255;
  const int bat = idx >> 10;

  const size_t base = ((size_t)((bat * 256 + lrow) * 256 + rblk * 64)) * 256;
  const float* Sblk = S + base;

  // stage S rows -> sA (bf16)
#pragma unroll
  for (int it = 0; it < 16; it++) {
    const int c = tid + it * 256;
    const int row = c >> 6, col = (c & 63) << 2;
    float4 v4 = *(const float4*)(Sblk + row * 256 + col);
    us4 p;
    p[0] = f2bf(v4.x); p[1] = f2bf(v4.y); p[2] = f2bf(v4.z); p[3] = f2bf(v4.w);
    *(us4*)(sA + row * LDA + col) = p;
  }
  __syncthreads();

  f32x4 acc[4][4];

  // ---- GEMM1: K = S@Wk + bk -> sB (bf16)
  mm64x256(sA, WkT, w, l16, lhi, acc);
  {
    float bkv[4];
#pragma unroll
    for (int nt = 0; nt < 4; nt++) bkv[nt] = bk[w * 64 + nt * 16 + l16];
#pragma unroll
    for (int rt = 0; rt < 4; rt++)
#pragma unroll
      for (int nt = 0; nt < 4; nt++)
#pragma unroll
        for (int rg = 0; rg < 4; rg++)
          sB[(rt * 16 + lhi * 4 + rg) * LDA + (w * 64 + nt * 16 + l16)] =
              f2bf(acc[rt][nt][rg] + bkv[nt]);
  }
  __syncthreads();

  // ---- GEMM2: scores = K @ q^T  (1/sqrt(D) folded into q)
  mm64x256(sB, q + bat * 65536, w, l16, lhi, acc);

  // ---- softmax over n (cols), cross-wave per row
#pragma unroll
  for (int rt = 0; rt < 4; rt++)
#pragma unroll
    for (int rg = 0; rg < 4; rg++) {
      float m = fmaxf(fmaxf(acc[rt][0][rg], acc[rt][1][rg]),
                      fmaxf(acc[rt][2][rg], acc[rt][3][rg]));
      m = fmaxf(m, __shfl_xor(m, 1));
      m = fmaxf(m, __shfl_xor(m, 2));
      m = fmaxf(m, __shfl_xor(m, 4));
      m = fmaxf(m, __shfl_xor(m, 8));
      if (l16 == 0) sRed[(rt * 16 + lhi * 4 + rg) * 8 + w] = m;
    }
  __syncthreads();
  float inv[4][4];
#pragma unroll
  for (int rt = 0; rt < 4; rt++)
#pragma unroll
    for (int rg = 0; rg < 4; rg++) {
      const int row = rt * 16 + lhi * 4 + rg;
      f32x4 mv = *(f32x4*)(sRed + row * 8);
      const float m = fmaxf(fmaxf(mv[0], mv[1]), fmaxf(mv[2], mv[3]));
      float s = 0.f;
#pragma unroll
      for (int nt = 0; nt < 4; nt++) {
        const float p = __expf(acc[rt][nt][rg] - m);
        acc[rt][nt][rg] = p;
        s += p;
      }
      s += __shfl_xor(s, 1);
      s += __shfl_xor(s, 2);
      s += __shfl_xor(s, 4);
      s += __shfl_xor(s, 8);
      if (l16 == 0) sRed[row * 8 + 4 + w] = s;
    }
  __syncthreads();
#pragma unroll
  for (int rt = 0; rt < 4; rt++)
#pragma unroll
    for (int rg = 0; rg < 4; rg++) {
      const int row = rt * 16 + lhi * 4 + rg;
      f32x4 sv = *(f32x4*)(sRed + row * 8 + 4);
      inv[rt][rg] = 1.f / (sv[0] + sv[1] + sv[2] + sv[3]);
    }
  // probs (normalized) -> sA (bf16)
#pragma unroll
  for (int rt = 0; rt < 4; rt++)
#pragma unroll
    for (int nt = 0; nt < 4; nt++)
#pragma unroll
      for (int rg = 0; rg < 4; rg++)
        sA[(rt * 16 + lhi * 4 + rg) * LDA + (w * 64 + nt * 16 + l16)] =
            f2bf(acc[rt][nt][rg] * inv[rt][rg]);
  __syncthreads();

  // ---- GEMM3: ctx = probs @ v -> sB (bf16)
  mm64x256(sA, vT + bat * 65536, w, l16, lhi, acc);
#pragma unroll
  for (int rt = 0; rt < 4; rt++)
#pragma unroll
    for (int nt = 0; nt < 4; nt++)
#pragma unroll
      for (int rg = 0; rg < 4; rg++)
        sB[(rt * 16 + lhi * 4 + rg) * LDA + (w * 64 + nt * 16 + l16)] =
            f2bf(acc[rt][nt][rg]);
  __syncthreads();

  // ---- GEMM4: out = ctx @ Wo
  mm64x256(sB, WoT, w, l16, lhi, acc);

  // ---- epilogue: + bo + S residual, LayerNorm over d, store f32
  float bov[4], gv[4], bev[4];
#pragma unroll
  for (int nt = 0; nt < 4; nt++) {
    const int col = w * 64 + nt * 16 + l16;
    bov[nt] = bo[col];
    gv[nt] = gamma[col];
    bev[nt] = beta[col];
  }
#pragma unroll
  for (int rt = 0; rt < 4; rt++)
#pragma unroll
    for (int rg = 0; rg < 4; rg++) {
      const int row = rt * 16 + lhi * 4 + rg;
      float s1 = 0.f, s2 = 0.f;
#pragma unroll
      for (int nt = 0; nt < 4; nt++) {
        const int col = w * 64 + nt * 16 + l16;
        const float val = acc[rt][nt][rg] + bov[nt] + Sblk[row * 256 + col];
        acc[rt][nt][rg] = val;
        s1 += val;
        s2 = fmaf(val, val, s2);
      }
      s1 += __shfl_xor(s1, 1); s2 += __shfl_xor(s2, 1);
      s1 += __shfl_xor(s1, 2); s2 += __shfl_xor(s2, 2);
      s1 += __shfl_xor(s1, 4); s2 += __shfl_xor(s2, 4);
      s1 += __shfl_xor(s1, 8); s2 += __shfl_xor(s2, 8);
      if (l16 == 0) { sRed[row * 8 + w] = s1; sRed[row * 8 + 4 + w] = s2; }
    }
  __syncthreads();
  float* O = out + base;
#pragma unroll
  for (int rt = 0; rt < 4; rt++)
#pragma unroll
    for (int rg = 0; rg < 4; rg++) {
      const int row = rt * 16 + lhi * 4 + rg;
      f32x4 sa = *(f32x4*)(sRed + row * 8);
      f32x4 sq = *(f32x4*)(sRed + row * 8 + 4);
      const float mean = (sa[0] + sa[1] + sa[2] + sa[3]) * (1.f / 256.f);
      const float ex2 = (sq[0] + sq[1] + sq[2] + sq[3]) * (1.f / 256.f);
      const float rstd = rsqrtf(ex2 - mean * mean + 1e-5f);
#pragma unroll
      for (int nt = 0; nt < 4; nt++) {
        const int col = w * 64 + nt * 16 + l16;
        O[row * 256 + col] = (acc[rt][nt][rg] - mean) * rstd * gv[nt] + bev[nt];
      }
    }
}

extern "C" void kernel_launch(void* const* d_in, const int* in_sizes, int n_in,
                              void* d_out, int out_size, void* d_ws, size_t ws_size,
                              hipStream_t stream) {
  const float* hs    = (const float*)d_in[0];
  const float* S     = (const float*)d_in[1];
  const float* Wq    = (const float*)d_in[2];
  const float* bq    = (const float*)d_in[3];
  const float* Wk    = (const float*)d_in[4];
  const float* bk    = (const float*)d_in[5];
  const float* Wv    = (const float*)d_in[6];
  const float* bv    = (const float*)d_in[7];
  const float* Wo    = (const float*)d_in[8];
  const float* bo    = (const float*)d_in[9];
  const float* gamma = (const float*)d_in[10];
  const float* beta  = (const float*)d_in[11];

  unsigned short* qb  = (unsigned short*)d_ws;          // 8*256*256 bf16
  unsigned short* vT  = qb + 8 * 256 * 256;             // 8*256*256 bf16
  unsigned short* WkT = vT + 8 * 256 * 256;             // 256*256 bf16
  unsigned short* WoT = WkT + 256 * 256;                // 256*256 bf16

  prep_qv<<<256, 256, 0, stream>>>(hs, Wq, bq, Wv, bv, qb, vT);
  conv_w<<<256, 256, 0, stream>>>(Wk, Wo, WkT, WoT);
  pair_attn<<<8192, 256, 0, stream>>>(S, bk, bo, gamma, beta, qb, vT, WkT, WoT,
                                      (float*)d_out);
}